// Round 2
// baseline (2692.744 us; speedup 1.0000x reference)
//
#include <hip/hip_runtime.h>
#include <math.h>

#define NA 10000
#define NE 100000
#define PI_F 3.14159265358979323846f

// Row layout of the "uncoupled" per-atom pack: c-blocks of 3^c rows, 32 k each.
// rowOff = {0,1,4,13}, total 40 rows = 1280 floats/atom.
// U concat offsets: U0@0 (1), U1@1 (12), U2@13 (81), U3@94 (432) => 526 floats.

__device__ __forceinline__ void stage_U(const float* __restrict__ U0,
                                        const float* __restrict__ U1,
                                        const float* __restrict__ U2,
                                        const float* __restrict__ U3,
                                        float* uLds, int t, int nthr) {
    for (int i = t; i < 526; i += nthr) {
        float v;
        if (i == 0)       v = U0[0];
        else if (i < 13)  v = U1[i - 1];
        else if (i < 94)  v = U2[i - 13];
        else              v = U3[i - 94];
        uLds[i] = v;
    }
}

// ---------------- Kernel A: per-atom uncoupled features (unc_f) ----------------
__global__ __launch_bounds__(256) void kA_uncf(
    const float* __restrict__ f0, const float* __restrict__ f1,
    const float* __restrict__ f2, const float* __restrict__ f3,
    const float* __restrict__ U0, const float* __restrict__ U1,
    const float* __restrict__ U2, const float* __restrict__ U3,
    float* __restrict__ uncf)
{
    __shared__ float uLds[526];
    const int t = threadIdx.x;
    stage_U(U0, U1, U2, U3, uLds, t, 256);
    __syncthreads();

    const int la = t >> 5, k = t & 31;
    const int a = blockIdx.x * 8 + la;
    float* op = uncf + (size_t)a * 1280;

    { // c = 0 (base 96)
        float x0 = f0[(size_t)a * 128 + 96 + k];
        op[k] = uLds[0] * x0;
    }
    { // c = 1 (base 64)
        float x[4];
        x[0] = f0[(size_t)a * 128 + 64 + k];
#pragma unroll
        for (int m = 0; m < 3; ++m) x[1 + m] = f1[(size_t)a * 288 + m * 96 + 64 + k];
#pragma unroll
        for (int d = 0; d < 3; ++d) {
            float acc = 0.f;
#pragma unroll
            for (int m = 0; m < 4; ++m) acc += uLds[1 + d * 4 + m] * x[m];
            op[(1 + d) * 32 + k] = acc;
        }
    }
    { // c = 2 (base 32)
        float x[9];
        x[0] = f0[(size_t)a * 128 + 32 + k];
#pragma unroll
        for (int m = 0; m < 3; ++m) x[1 + m] = f1[(size_t)a * 288 + m * 96 + 32 + k];
#pragma unroll
        for (int m = 0; m < 5; ++m) x[4 + m] = f2[(size_t)a * 320 + m * 64 + 32 + k];
#pragma unroll
        for (int d = 0; d < 9; ++d) {
            float acc = 0.f;
#pragma unroll
            for (int m = 0; m < 9; ++m) acc += uLds[13 + d * 9 + m] * x[m];
            op[(4 + d) * 32 + k] = acc;
        }
    }
    { // c = 3 (base 0)
        float x[16];
        x[0] = f0[(size_t)a * 128 + k];
#pragma unroll
        for (int m = 0; m < 3; ++m) x[1 + m] = f1[(size_t)a * 288 + m * 96 + k];
#pragma unroll
        for (int m = 0; m < 5; ++m) x[4 + m] = f2[(size_t)a * 320 + m * 64 + k];
#pragma unroll
        for (int m = 0; m < 7; ++m) x[9 + m] = f3[(size_t)a * 224 + m * 32 + k];
#pragma unroll
        for (int d = 0; d < 27; ++d) {
            float acc = 0.f;
#pragma unroll
            for (int m = 0; m < 16; ++m) acc += uLds[94 + d * 16 + m] * x[m];
            op[(13 + d) * 32 + k] = acc;
        }
    }
}

// ---------------- CSR build: count / scan / scatter ----------------
__global__ __launch_bounds__(256) void kCount(const int* __restrict__ centers,
                                              int* __restrict__ counts)
{
    const int e = blockIdx.x * 256 + threadIdx.x;
    if (e < NE) atomicAdd(&counts[centers[e]], 1);
}

__global__ __launch_bounds__(1024) void kScan(const int* __restrict__ counts,
                                              int* __restrict__ offsets,
                                              int* __restrict__ cursor)
{
    __shared__ int sums[1024];
    const int t = threadIdx.x;
    const int base = t * 10;
    int local[10];
    int s = 0;
#pragma unroll
    for (int j = 0; j < 10; ++j) {
        int idx = base + j;
        int v = (idx < NA) ? counts[idx] : 0;
        local[j] = s;
        s += v;
    }
    sums[t] = s;
    __syncthreads();
    for (int off = 1; off < 1024; off <<= 1) {
        int v = (t >= off) ? sums[t - off] : 0;
        __syncthreads();
        sums[t] += v;
        __syncthreads();
    }
    const int prev = (t == 0) ? 0 : sums[t - 1];
#pragma unroll
    for (int j = 0; j < 10; ++j) {
        int idx = base + j;
        if (idx <= NA) {
            int o = prev + local[j];
            offsets[idx] = o;
            if (idx < NA) cursor[idx] = o;
        }
    }
}

__global__ __launch_bounds__(256) void kScatter(const int* __restrict__ centers,
                                                int* __restrict__ cursor,
                                                int* __restrict__ order)
{
    const int e = blockIdx.x * 256 + threadIdx.x;
    if (e < NE) {
        int c = centers[e];
        int pos = atomicAdd(&cursor[c], 1);
        order[pos] = e;
    }
}

// ---------------- Kernel B2: per-ATOM message accumulation (no atomics) -------
// 8 atoms per 256-block; 32 k-lanes per atom; 40 register accumulators/lane.
__global__ __launch_bounds__(256) void kB2(
    const float* __restrict__ r,
    const float* __restrict__ sh0, const float* __restrict__ sh1,
    const float* __restrict__ sh2, const float* __restrict__ sh3,
    const float* __restrict__ Wr0, const float* __restrict__ Wr1,
    const float* __restrict__ Wr2, const float* __restrict__ Wr3,
    const float* __restrict__ U0, const float* __restrict__ U1,
    const float* __restrict__ U2, const float* __restrict__ U3,
    const int* __restrict__ offsets, const int* __restrict__ order,
    const int* __restrict__ neighbors,
    const float* __restrict__ uncf, float* __restrict__ pooled)
{
    __shared__ float uLds[526];
    __shared__ float wLds[2560];      // Wrad0..3 concat: 1024,768,512,256
    const int t = threadIdx.x;
    stage_U(U0, U1, U2, U3, uLds, t, 256);
    for (int i = t; i < 2560; i += 256) {
        float v;
        if (i < 1024)      v = Wr0[i];
        else if (i < 1792) v = Wr1[i - 1024];
        else if (i < 2304) v = Wr2[i - 1792];
        else               v = Wr3[i - 2304];
        wLds[i] = v;
    }
    __syncthreads();

    const int la = t >> 5, k = t & 31;
    const int a = blockIdx.x * 8 + la;
    const int beg = offsets[a], end = offsets[a + 1];

    float acc[40];
#pragma unroll
    for (int i = 0; i < 40; ++i) acc[i] = 0.f;

    const int KL[4] = {128, 96, 64, 32};
    const int WO[4] = {0, 1024, 1792, 2304};
    const int UO[4] = {0, 1, 13, 94};
    const int RO[4] = {0, 1, 4, 13};
    const int P3[4] = {1, 3, 9, 27};

    for (int i = beg; i < end; ++i) {
        const int e = order[i];

        // sh (16 floats, uniform across the 32-lane group -> broadcast loads)
        float shv[16];
        shv[0] = sh0[e];
#pragma unroll
        for (int m = 0; m < 3; ++m) shv[1 + m] = sh1[(size_t)e * 3 + m];
#pragma unroll
        for (int m = 0; m < 5; ++m) shv[4 + m] = sh2[(size_t)e * 5 + m];
#pragma unroll
        for (int m = 0; m < 7; ++m) shv[9 + m] = sh3[(size_t)e * 7 + m];

        const float rv = r[e];
        const float fc = 0.5f * (cosf(PI_F * fminf(rv * 0.2f, 1.0f)) + 1.0f);
        const float pref = fc / (rv + 1e-6f);
        const float step = rv * (PI_F * 0.2f);
        float rb[8];
#pragma unroll
        for (int n = 0; n < 8; ++n) rb[n] = sinf((float)(n + 1) * step) * pref;

        float rad[4][4];
#pragma unroll
        for (int lp = 0; lp < 4; ++lp) {
#pragma unroll
            for (int c = 0; c < 4; ++c) {
                if (c < lp) continue;
                const int base = 32 * (3 - c);
                float s = 0.f;
#pragma unroll
                for (int n = 0; n < 8; ++n)
                    s += rb[n] * wLds[WO[lp] + n * KL[lp] + base + k];
                rad[lp][c] = s;
            }
        }

        const int nbr = neighbors[e];
        const float* uf = uncf + (size_t)nbr * 1280 + k;

#pragma unroll
        for (int c = 0; c < 4; ++c) {
            const int M2 = (c + 1) * (c + 1);
#pragma unroll
            for (int d = 0; d < P3[c]; ++d) {
                float uv = 0.f;
#pragma unroll
                for (int lp = 0; lp <= c; ++lp) {
                    float s = 0.f;
#pragma unroll
                    for (int ml = 0; ml < 2 * lp + 1; ++ml)
                        s += uLds[UO[c] + d * M2 + lp * lp + ml] * shv[lp * lp + ml];
                    uv += s * rad[lp][c];
                }
                const int row = RO[c] + d;
                acc[row] += uv * uf[row * 32];
            }
        }
    }

    float* pl = pooled + (size_t)a * 1280 + k;
#pragma unroll
    for (int row = 0; row < 40; ++row) pl[row * 32] = acc[row];
}

// ---------------- Kernel C: couple back + linear + residual ----------------
__global__ __launch_bounds__(256) void kC_out(
    const float* __restrict__ pooled,
    const float* __restrict__ f0, const float* __restrict__ f1,
    const float* __restrict__ f2, const float* __restrict__ f3,
    const float* __restrict__ U0, const float* __restrict__ U1,
    const float* __restrict__ U2, const float* __restrict__ U3,
    const float* __restrict__ W0, const float* __restrict__ W1,
    const float* __restrict__ W2, const float* __restrict__ W3,
    float* __restrict__ out)
{
    __shared__ float uLds[526];
    __shared__ float plds[4 * 1280];
    __shared__ float clds[4 * 960];   // coupled: c-blocks {32,128,288,512} @ {0,32,160,448}
    const int t = threadIdx.x;
    stage_U(U0, U1, U2, U3, uLds, t, 256);
    const int a0 = blockIdx.x * 4;
    for (int i = t; i < 5120; i += 256) plds[i] = pooled[(size_t)a0 * 1280 + i];
    __syncthreads();

    for (int idx = t; idx < 3840; idx += 256) {
        const int la = idx / 960;
        const int rem = idx - la * 960;
        int c, off;
        if (rem < 32)       { c = 0; off = 0; }
        else if (rem < 160) { c = 1; off = 32; }
        else if (rem < 448) { c = 2; off = 160; }
        else                { c = 3; off = 448; }
        const int r2 = rem - off;
        const int m = r2 >> 5, k = r2 & 31;
        const int M2 = (c + 1) * (c + 1);
        const int UOc = (c == 0 ? 0 : c == 1 ? 1 : c == 2 ? 13 : 94);
        const int ROc = (c == 0 ? 0 : c == 1 ? 1 : c == 2 ? 4 : 13);
        const int nd  = (c == 0 ? 1 : c == 1 ? 3 : c == 2 ? 9 : 27);
        float acc = 0.f;
        for (int d = 0; d < nd; ++d)
            acc += uLds[UOc + d * M2 + m] * plds[la * 1280 + (ROc + d) * 32 + k];
        clds[idx] = acc;
    }
    __syncthreads();

    const float* Fp[4] = {f0, f1, f2, f3};
    const float* Wp[4] = {W0, W1, W2, W3};
    const int Kl[4] = {128, 96, 64, 32};
    const int Ml[4] = {1, 3, 5, 7};
    const size_t Ol[4] = {0, 1280000, 4160000, 7360000};
    const int CO[4] = {0, 32, 160, 448};
#pragma unroll
    for (int l = 0; l < 4; ++l) {
        const int K = Kl[l], M = Ml[l], MK = M * K;
        const float* W = Wp[l];
        const float* F = Fp[l];
        for (int idx = t; idx < MK; idx += 256) {
            const int m = idx / K, q = idx - m * K;
            float acc[4];
#pragma unroll
            for (int la = 0; la < 4; ++la)
                acc[la] = F[(size_t)(a0 + la) * MK + idx];
#pragma unroll
            for (int j = 0; j < 4 - l; ++j) {
                const int c = l + j;
                const int cb = CO[c] + (l * l + m) * 32;
#pragma unroll
                for (int k = 0; k < 32; ++k) {
                    const float w = W[(size_t)(32 * j + k) * K + q];
#pragma unroll
                    for (int la = 0; la < 4; ++la)
                        acc[la] += clds[la * 960 + cb + k] * w;
                }
            }
#pragma unroll
            for (int la = 0; la < 4; ++la)
                out[Ol[l] + (size_t)(a0 + la) * MK + idx] = acc[la];
        }
    }
}

extern "C" void kernel_launch(void* const* d_in, const int* in_sizes, int n_in,
                              void* d_out, int out_size, void* d_ws, size_t ws_size,
                              hipStream_t stream)
{
    int ir, ish[4], ift[4], iwr[4], iu[4], iwl[4], ic, in_;
    if (in_sizes[2] == 300000) {
        // signature order
        ir = 0;
        for (int l = 0; l < 4; ++l) { ish[l] = 1 + l; ift[l] = 5 + l; iwr[l] = 9 + l; iu[l] = 13 + l; iwl[l] = 17 + l; }
        ic = 21; in_ = 22;
    } else {
        ir = 0;
        for (int l = 0; l < 4; ++l) { ish[l] = 1 + 5 * l; ift[l] = 2 + 5 * l; iwr[l] = 3 + 5 * l; iu[l] = 4 + 5 * l; iwl[l] = 5 + 5 * l; }
        ic = 21; in_ = 22;
    }
    const float* r   = (const float*)d_in[ir];
    const float* sh0 = (const float*)d_in[ish[0]];
    const float* sh1 = (const float*)d_in[ish[1]];
    const float* sh2 = (const float*)d_in[ish[2]];
    const float* sh3 = (const float*)d_in[ish[3]];
    const float* f0  = (const float*)d_in[ift[0]];
    const float* f1  = (const float*)d_in[ift[1]];
    const float* f2  = (const float*)d_in[ift[2]];
    const float* f3  = (const float*)d_in[ift[3]];
    const float* Wr0 = (const float*)d_in[iwr[0]];
    const float* Wr1 = (const float*)d_in[iwr[1]];
    const float* Wr2 = (const float*)d_in[iwr[2]];
    const float* Wr3 = (const float*)d_in[iwr[3]];
    const float* U0  = (const float*)d_in[iu[0]];
    const float* U1  = (const float*)d_in[iu[1]];
    const float* U2  = (const float*)d_in[iu[2]];
    const float* U3  = (const float*)d_in[iu[3]];
    const float* Wl0 = (const float*)d_in[iwl[0]];
    const float* Wl1 = (const float*)d_in[iwl[1]];
    const float* Wl2 = (const float*)d_in[iwl[2]];
    const float* Wl3 = (const float*)d_in[iwl[3]];
    const int* centers   = (const int*)d_in[ic];
    const int* neighbors = (const int*)d_in[in_];

    float* uncf   = (float*)d_ws;                      // 12.8M floats = 51.2 MB
    float* pooled = uncf + (size_t)NA * 1280;          // 12.8M floats = 51.2 MB
    int*   counts  = (int*)(pooled + (size_t)NA * 1280);
    int*   offsets = counts + NA;                      // NA+1
    int*   cursor  = offsets + NA + 1;                 // NA
    int*   order   = cursor + NA;                      // NE
    float* outp   = (float*)d_out;

    hipMemsetAsync(counts, 0, NA * sizeof(int), stream);
    kA_uncf<<<NA / 8, 256, 0, stream>>>(f0, f1, f2, f3, U0, U1, U2, U3, uncf);
    kCount<<<(NE + 255) / 256, 256, 0, stream>>>(centers, counts);
    kScan<<<1, 1024, 0, stream>>>(counts, offsets, cursor);
    kScatter<<<(NE + 255) / 256, 256, 0, stream>>>(centers, cursor, order);
    kB2<<<NA / 8, 256, 0, stream>>>(r, sh0, sh1, sh2, sh3, Wr0, Wr1, Wr2, Wr3,
                                    U0, U1, U2, U3, offsets, order, neighbors,
                                    uncf, pooled);
    kC_out<<<NA / 4, 256, 0, stream>>>(pooled, f0, f1, f2, f3, U0, U1, U2, U3,
                                       Wl0, Wl1, Wl2, Wl3, outp);
}

// Round 3
// 734.658 us; speedup vs baseline: 3.6653x; 3.6653x over previous
//
#include <hip/hip_runtime.h>
#include <math.h>

#define NA 10000
#define NE 100000
#define PI_F 3.14159265358979323846f

// Row layout of the "uncoupled" per-atom pack: c-blocks of 3^c rows, 32 k each.
// rowOff = {0,1,4,13}, total 40 rows = 1280 floats/atom.
// U concat offsets: U0@0 (1), U1@1 (12), U2@13 (81), U3@94 (432) => 526 floats.

__device__ __forceinline__ void stage_U(const float* __restrict__ U0,
                                        const float* __restrict__ U1,
                                        const float* __restrict__ U2,
                                        const float* __restrict__ U3,
                                        float* uLds, int t, int nthr) {
    for (int i = t; i < 526; i += nthr) {
        float v;
        if (i == 0)       v = U0[0];
        else if (i < 13)  v = U1[i - 1];
        else if (i < 94)  v = U2[i - 13];
        else              v = U3[i - 94];
        uLds[i] = v;
    }
}

// ---------------- Kernel A: per-atom uncoupled features (unc_f) ----------------
__global__ __launch_bounds__(256) void kA_uncf(
    const float* __restrict__ f0, const float* __restrict__ f1,
    const float* __restrict__ f2, const float* __restrict__ f3,
    const float* __restrict__ U0, const float* __restrict__ U1,
    const float* __restrict__ U2, const float* __restrict__ U3,
    float* __restrict__ uncf)
{
    __shared__ float uLds[526];
    const int t = threadIdx.x;
    stage_U(U0, U1, U2, U3, uLds, t, 256);
    __syncthreads();

    const int la = t >> 5, k = t & 31;
    const int a = blockIdx.x * 8 + la;
    float* op = uncf + (size_t)a * 1280;

    { // c = 0 (base 96)
        float x0 = f0[(size_t)a * 128 + 96 + k];
        op[k] = uLds[0] * x0;
    }
    { // c = 1 (base 64)
        float x[4];
        x[0] = f0[(size_t)a * 128 + 64 + k];
#pragma unroll
        for (int m = 0; m < 3; ++m) x[1 + m] = f1[(size_t)a * 288 + m * 96 + 64 + k];
#pragma unroll
        for (int d = 0; d < 3; ++d) {
            float acc = 0.f;
#pragma unroll
            for (int m = 0; m < 4; ++m) acc += uLds[1 + d * 4 + m] * x[m];
            op[(1 + d) * 32 + k] = acc;
        }
    }
    { // c = 2 (base 32)
        float x[9];
        x[0] = f0[(size_t)a * 128 + 32 + k];
#pragma unroll
        for (int m = 0; m < 3; ++m) x[1 + m] = f1[(size_t)a * 288 + m * 96 + 32 + k];
#pragma unroll
        for (int m = 0; m < 5; ++m) x[4 + m] = f2[(size_t)a * 320 + m * 64 + 32 + k];
#pragma unroll
        for (int d = 0; d < 9; ++d) {
            float acc = 0.f;
#pragma unroll
            for (int m = 0; m < 9; ++m) acc += uLds[13 + d * 9 + m] * x[m];
            op[(4 + d) * 32 + k] = acc;
        }
    }
    { // c = 3 (base 0)
        float x[16];
        x[0] = f0[(size_t)a * 128 + k];
#pragma unroll
        for (int m = 0; m < 3; ++m) x[1 + m] = f1[(size_t)a * 288 + m * 96 + k];
#pragma unroll
        for (int m = 0; m < 5; ++m) x[4 + m] = f2[(size_t)a * 320 + m * 64 + k];
#pragma unroll
        for (int m = 0; m < 7; ++m) x[9 + m] = f3[(size_t)a * 224 + m * 32 + k];
#pragma unroll
        for (int d = 0; d < 27; ++d) {
            float acc = 0.f;
#pragma unroll
            for (int m = 0; m < 16; ++m) acc += uLds[94 + d * 16 + m] * x[m];
            op[(13 + d) * 32 + k] = acc;
        }
    }
}

// ---------------- Kernel E: per-edge U.sh coefficients + radial basis --------
// csbuf layout: row-major-by-row, [row][e][4] -> csbuf[(row*NE + e)*4 + lp]
// rbbuf layout: [e][8]
__global__ __launch_bounds__(256) void kE(
    const float* __restrict__ r,
    const float* __restrict__ sh0, const float* __restrict__ sh1,
    const float* __restrict__ sh2, const float* __restrict__ sh3,
    const float* __restrict__ U0, const float* __restrict__ U1,
    const float* __restrict__ U2, const float* __restrict__ U3,
    float* __restrict__ rbbuf, float* __restrict__ csbuf)
{
    __shared__ float uLds[526];
    stage_U(U0, U1, U2, U3, uLds, threadIdx.x, 256);
    __syncthreads();
    const int e = blockIdx.x * 256 + threadIdx.x;
    if (e >= NE) return;

    float shv[16];
    shv[0] = sh0[e];
#pragma unroll
    for (int m = 0; m < 3; ++m) shv[1 + m] = sh1[(size_t)e * 3 + m];
#pragma unroll
    for (int m = 0; m < 5; ++m) shv[4 + m] = sh2[(size_t)e * 5 + m];
#pragma unroll
    for (int m = 0; m < 7; ++m) shv[9 + m] = sh3[(size_t)e * 7 + m];

    const float rv = r[e];
    const float fc = 0.5f * (cosf(PI_F * fminf(rv * 0.2f, 1.0f)) + 1.0f);
    const float pref = fc / (rv + 1e-6f);
    const float step = rv * (PI_F * 0.2f);
    float4 ra, rb;
    ra.x = sinf(1.f * step) * pref; ra.y = sinf(2.f * step) * pref;
    ra.z = sinf(3.f * step) * pref; ra.w = sinf(4.f * step) * pref;
    rb.x = sinf(5.f * step) * pref; rb.y = sinf(6.f * step) * pref;
    rb.z = sinf(7.f * step) * pref; rb.w = sinf(8.f * step) * pref;
    *(float4*)(rbbuf + (size_t)e * 8)     = ra;
    *(float4*)(rbbuf + (size_t)e * 8 + 4) = rb;

    const int UO[4] = {0, 1, 13, 94};
    const int RO[4] = {0, 1, 4, 13};
    const int P3[4] = {1, 3, 9, 27};
#pragma unroll
    for (int c = 0; c < 4; ++c) {
        const int M2 = (c + 1) * (c + 1);
        for (int d = 0; d < P3[c]; ++d) {
            float4 cv = make_float4(0.f, 0.f, 0.f, 0.f);
            float* cvp = &cv.x;
#pragma unroll
            for (int lp = 0; lp < 4; ++lp) {
                if (lp > c) break;
                float s = 0.f;
#pragma unroll
                for (int ml = 0; ml < 2 * lp + 1; ++ml)
                    s += uLds[UO[c] + d * M2 + lp * lp + ml] * shv[lp * lp + ml];
                cvp[lp] = s;
            }
            *(float4*)(csbuf + ((size_t)(RO[c] + d) * NE + e) * 4) = cv;
        }
    }
}

// ---------------- CSR build: count / scan / scatter ----------------
__global__ __launch_bounds__(256) void kCount(const int* __restrict__ centers,
                                              int* __restrict__ counts)
{
    const int e = blockIdx.x * 256 + threadIdx.x;
    if (e < NE) atomicAdd(&counts[centers[e]], 1);
}

__global__ __launch_bounds__(1024) void kScan(const int* __restrict__ counts,
                                              int* __restrict__ offsets,
                                              int* __restrict__ cursor)
{
    __shared__ int sums[1024];
    const int t = threadIdx.x;
    const int base = t * 10;
    int local[10];
    int s = 0;
#pragma unroll
    for (int j = 0; j < 10; ++j) {
        int idx = base + j;
        int v = (idx < NA) ? counts[idx] : 0;
        local[j] = s;
        s += v;
    }
    sums[t] = s;
    __syncthreads();
    for (int off = 1; off < 1024; off <<= 1) {
        int v = (t >= off) ? sums[t - off] : 0;
        __syncthreads();
        sums[t] += v;
        __syncthreads();
    }
    const int prev = (t == 0) ? 0 : sums[t - 1];
#pragma unroll
    for (int j = 0; j < 10; ++j) {
        int idx = base + j;
        if (idx <= NA) {
            int o = prev + local[j];
            offsets[idx] = o;
            if (idx < NA) cursor[idx] = o;
        }
    }
}

__global__ __launch_bounds__(256) void kScatter(const int* __restrict__ centers,
                                                int* __restrict__ cursor,
                                                int* __restrict__ order)
{
    const int e = blockIdx.x * 256 + threadIdx.x;
    if (e < NE) {
        int c = centers[e];
        int pos = atomicAdd(&cursor[c], 1);
        order[pos] = e;
    }
}

// ---------------- Kernel B2: per-ATOM accumulation, 8 edge-slots x 32 lanes ---
__global__ __launch_bounds__(256, 3) void kB2(
    const float* __restrict__ Wr0, const float* __restrict__ Wr1,
    const float* __restrict__ Wr2, const float* __restrict__ Wr3,
    const int* __restrict__ offsets, const int* __restrict__ order,
    const int* __restrict__ neighbors,
    const float* __restrict__ rbbuf, const float* __restrict__ csbuf,
    const float* __restrict__ uncf, float* __restrict__ pooled)
{
    __shared__ float wLds[2560];      // Wrad0..3 concat: 1024,768,512,256
    __shared__ float red[8 * 1280];
    const int t = threadIdx.x;
    for (int i = t; i < 2560; i += 256) {
        float v;
        if (i < 1024)      v = Wr0[i];
        else if (i < 1792) v = Wr1[i - 1024];
        else if (i < 2304) v = Wr2[i - 1792];
        else               v = Wr3[i - 2304];
        wLds[i] = v;
    }
    __syncthreads();

    const int g = t >> 5, k = t & 31;
    const int a = blockIdx.x;
    const int beg = offsets[a], end = offsets[a + 1];

    float acc[40];
#pragma unroll
    for (int i = 0; i < 40; ++i) acc[i] = 0.f;

    const int KL[4] = {128, 96, 64, 32};
    const int WO[4] = {0, 1024, 1792, 2304};

    for (int i = beg + g; i < end; i += 8) {
        const int e = order[i];
        const int nbr = neighbors[e];
        const float* uf = uncf + (size_t)nbr * 1280 + k;

        const float4 r0 = *(const float4*)(rbbuf + (size_t)e * 8);
        const float4 r1 = *(const float4*)(rbbuf + (size_t)e * 8 + 4);
        const float rb[8] = {r0.x, r0.y, r0.z, r0.w, r1.x, r1.y, r1.z, r1.w};

        float rad[4][4];
#pragma unroll
        for (int lp = 0; lp < 4; ++lp) {
#pragma unroll
            for (int c = 0; c < 4; ++c) {
                if (c < lp) continue;
                const int base = 32 * (3 - c);
                float s = 0.f;
#pragma unroll
                for (int n = 0; n < 8; ++n)
                    s += rb[n] * wLds[WO[lp] + n * KL[lp] + base + k];
                rad[lp][c] = s;
            }
        }

#pragma unroll
        for (int row = 0; row < 40; ++row) {
            const int c = (row == 0) ? 0 : (row < 4) ? 1 : (row < 13) ? 2 : 3;
            const float4 cv = *(const float4*)(csbuf + ((size_t)row * NE + e) * 4);
            float uv = cv.x * rad[0][c];
            if (c >= 1) uv += cv.y * rad[1][c];
            if (c >= 2) uv += cv.z * rad[2][c];
            if (c >= 3) uv += cv.w * rad[3][c];
            acc[row] += uv * uf[row * 32];
        }
    }

#pragma unroll
    for (int row = 0; row < 40; ++row) red[g * 1280 + row * 32 + k] = acc[row];
    __syncthreads();

    for (int idx = t; idx < 1280; idx += 256) {
        float s = 0.f;
#pragma unroll
        for (int gg = 0; gg < 8; ++gg) s += red[gg * 1280 + idx];
        pooled[(size_t)a * 1280 + idx] = s;
    }
}

// ---------------- Kernel C: couple back + linear + residual ----------------
__global__ __launch_bounds__(256) void kC_out(
    const float* __restrict__ pooled,
    const float* __restrict__ f0, const float* __restrict__ f1,
    const float* __restrict__ f2, const float* __restrict__ f3,
    const float* __restrict__ U0, const float* __restrict__ U1,
    const float* __restrict__ U2, const float* __restrict__ U3,
    const float* __restrict__ W0, const float* __restrict__ W1,
    const float* __restrict__ W2, const float* __restrict__ W3,
    float* __restrict__ out)
{
    __shared__ float uLds[526];
    __shared__ float plds[4 * 1280];
    __shared__ float clds[4 * 960];   // coupled: c-blocks {32,128,288,512} @ {0,32,160,448}
    const int t = threadIdx.x;
    stage_U(U0, U1, U2, U3, uLds, t, 256);
    const int a0 = blockIdx.x * 4;
    for (int i = t; i < 5120; i += 256) plds[i] = pooled[(size_t)a0 * 1280 + i];
    __syncthreads();

    for (int idx = t; idx < 3840; idx += 256) {
        const int la = idx / 960;
        const int rem = idx - la * 960;
        int c, off;
        if (rem < 32)       { c = 0; off = 0; }
        else if (rem < 160) { c = 1; off = 32; }
        else if (rem < 448) { c = 2; off = 160; }
        else                { c = 3; off = 448; }
        const int r2 = rem - off;
        const int m = r2 >> 5, k = r2 & 31;
        const int M2 = (c + 1) * (c + 1);
        const int UOc = (c == 0 ? 0 : c == 1 ? 1 : c == 2 ? 13 : 94);
        const int ROc = (c == 0 ? 0 : c == 1 ? 1 : c == 2 ? 4 : 13);
        const int nd  = (c == 0 ? 1 : c == 1 ? 3 : c == 2 ? 9 : 27);
        float acc = 0.f;
        for (int d = 0; d < nd; ++d)
            acc += uLds[UOc + d * M2 + m] * plds[la * 1280 + (ROc + d) * 32 + k];
        clds[idx] = acc;
    }
    __syncthreads();

    const float* Fp[4] = {f0, f1, f2, f3};
    const float* Wp[4] = {W0, W1, W2, W3};
    const int Kl[4] = {128, 96, 64, 32};
    const int Ml[4] = {1, 3, 5, 7};
    const size_t Ol[4] = {0, 1280000, 4160000, 7360000};
    const int CO[4] = {0, 32, 160, 448};
#pragma unroll
    for (int l = 0; l < 4; ++l) {
        const int K = Kl[l], M = Ml[l], MK = M * K;
        const float* W = Wp[l];
        const float* F = Fp[l];
        for (int idx = t; idx < MK; idx += 256) {
            const int m = idx / K, q = idx - m * K;
            float acc[4];
#pragma unroll
            for (int la = 0; la < 4; ++la)
                acc[la] = F[(size_t)(a0 + la) * MK + idx];
#pragma unroll
            for (int j = 0; j < 4 - l; ++j) {
                const int c = l + j;
                const int cb = CO[c] + (l * l + m) * 32;
#pragma unroll
                for (int k = 0; k < 32; ++k) {
                    const float w = W[(size_t)(32 * j + k) * K + q];
#pragma unroll
                    for (int la = 0; la < 4; ++la)
                        acc[la] += clds[la * 960 + cb + k] * w;
                }
            }
#pragma unroll
            for (int la = 0; la < 4; ++la)
                out[Ol[l] + (size_t)(a0 + la) * MK + idx] = acc[la];
        }
    }
}

extern "C" void kernel_launch(void* const* d_in, const int* in_sizes, int n_in,
                              void* d_out, int out_size, void* d_ws, size_t ws_size,
                              hipStream_t stream)
{
    int ir, ish[4], ift[4], iwr[4], iu[4], iwl[4], ic, in_;
    if (in_sizes[2] == 300000) {
        // signature order
        ir = 0;
        for (int l = 0; l < 4; ++l) { ish[l] = 1 + l; ift[l] = 5 + l; iwr[l] = 9 + l; iu[l] = 13 + l; iwl[l] = 17 + l; }
        ic = 21; in_ = 22;
    } else {
        ir = 0;
        for (int l = 0; l < 4; ++l) { ish[l] = 1 + 5 * l; ift[l] = 2 + 5 * l; iwr[l] = 3 + 5 * l; iu[l] = 4 + 5 * l; iwl[l] = 5 + 5 * l; }
        ic = 21; in_ = 22;
    }
    const float* r   = (const float*)d_in[ir];
    const float* sh0 = (const float*)d_in[ish[0]];
    const float* sh1 = (const float*)d_in[ish[1]];
    const float* sh2 = (const float*)d_in[ish[2]];
    const float* sh3 = (const float*)d_in[ish[3]];
    const float* f0  = (const float*)d_in[ift[0]];
    const float* f1  = (const float*)d_in[ift[1]];
    const float* f2  = (const float*)d_in[ift[2]];
    const float* f3  = (const float*)d_in[ift[3]];
    const float* Wr0 = (const float*)d_in[iwr[0]];
    const float* Wr1 = (const float*)d_in[iwr[1]];
    const float* Wr2 = (const float*)d_in[iwr[2]];
    const float* Wr3 = (const float*)d_in[iwr[3]];
    const float* U0  = (const float*)d_in[iu[0]];
    const float* U1  = (const float*)d_in[iu[1]];
    const float* U2  = (const float*)d_in[iu[2]];
    const float* U3  = (const float*)d_in[iu[3]];
    const float* Wl0 = (const float*)d_in[iwl[0]];
    const float* Wl1 = (const float*)d_in[iwl[1]];
    const float* Wl2 = (const float*)d_in[iwl[2]];
    const float* Wl3 = (const float*)d_in[iwl[3]];
    const int* centers   = (const int*)d_in[ic];
    const int* neighbors = (const int*)d_in[in_];

    float* uncf   = (float*)d_ws;                       // 12.8M floats
    float* pooled = uncf + (size_t)NA * 1280;           // 12.8M floats
    float* rbbuf  = pooled + (size_t)NA * 1280;         // 0.8M floats
    float* csbuf  = rbbuf + (size_t)NE * 8;             // 16M floats
    int*   counts  = (int*)(csbuf + (size_t)40 * NE * 4);
    int*   offsets = counts + NA;                       // NA+1
    int*   cursor  = offsets + NA + 1;                  // NA
    int*   order   = cursor + NA;                       // NE
    float* outp   = (float*)d_out;

    hipMemsetAsync(counts, 0, NA * sizeof(int), stream);
    kA_uncf<<<NA / 8, 256, 0, stream>>>(f0, f1, f2, f3, U0, U1, U2, U3, uncf);
    kE<<<(NE + 255) / 256, 256, 0, stream>>>(r, sh0, sh1, sh2, sh3,
                                             U0, U1, U2, U3, rbbuf, csbuf);
    kCount<<<(NE + 255) / 256, 256, 0, stream>>>(centers, counts);
    kScan<<<1, 1024, 0, stream>>>(counts, offsets, cursor);
    kScatter<<<(NE + 255) / 256, 256, 0, stream>>>(centers, cursor, order);
    kB2<<<NA, 256, 0, stream>>>(Wr0, Wr1, Wr2, Wr3, offsets, order, neighbors,
                                rbbuf, csbuf, uncf, pooled);
    kC_out<<<NA / 4, 256, 0, stream>>>(pooled, f0, f1, f2, f3, U0, U1, U2, U3,
                                       Wl0, Wl1, Wl2, Wl3, outp);
}